// Round 2
// baseline (10121.473 us; speedup 1.0000x reference)
//
#include <hip/hip_runtime.h>

// RLIF forward, persistent-kernel version.
// - One workgroup per CU (grid 256, 1 wg/CU co-resident), T-loop inside.
// - Wr staged once into LDS as exact 3-way bf16 split (h+m+l == w bitwise).
// - GEMM via v_mfma_f32_16x16x32_bf16; y is binary so bf16 operands are exact.
// - y_prev read from out[t-1] slab (f32 0/1 -> bf16 via >>16, exact). No WAR race.
// - Group barrier: only the 64 wgs sharing a batch-block sync each step.

#define T_STEPS 256
#define BATCH   128
#define NNEUR   1024
#define DECAY_F 0.2f
#define THRESH  0.3f
#define NGROUPS 4     // batch-blocks (bb), 32 batches each
#define WPG     64    // workgroups per group (ib count)

typedef __attribute__((ext_vector_type(8))) short short8;
typedef __attribute__((ext_vector_type(4))) float f32x4;

union U8 { short8 s; unsigned u[4]; };

__device__ __forceinline__ unsigned short f2bf_rn(float x) {
    unsigned u = __float_as_uint(x);
    return (unsigned short)((u + 0x7FFFu + ((u >> 16) & 1u)) >> 16);
}

__global__ void rlif_init(int* __restrict__ cnt) {
    int i = blockIdx.x * 256 + threadIdx.x;
    if (i < T_STEPS * NGROUPS) cnt[i] = 0;
}

__global__ __launch_bounds__(256, 1)
void rlif_persist(const float* __restrict__ tx,   // [T][B][N]
                  const float* __restrict__ Wr,   // [N][N]
                  const float* __restrict__ br,   // [N]
                  float* __restrict__ out,        // [T][B][N]
                  int* __restrict__ cnt)          // [NGROUPS][T]
{
    extern __shared__ char smem[];
    unsigned short* wlds = (unsigned short*)smem;      // 3 mats * [16][1024] bf16, swizzled
    float* red = (float*)(smem + 3 * 16 * 1024 * 2);   // [2][16][16] f32 k-reduce buf

    const int tid = threadIdx.x;
    const int bb  = blockIdx.x >> 6;   // 0..3  batch-block
    const int ib  = blockIdx.x & 63;   // 0..63 neuron-block
    const int i0  = ib * 16;
    const int b0  = bb * 32;
    const int w   = tid >> 6;          // wave 0..3
    const int l   = tid & 63;
    const int c   = l & 15;            // frag row/col lane
    const int kg  = l >> 4;            // 0..3 k-chunk within frag
    const int r   = w & 1;             // row-tile (which 16 batches)
    const int h   = w >> 1;            // k-half (0: k<512, 1: k>=512)

    // ---- one-time: stage Wr rows [i0, i0+16) as exact 3-way bf16 split, swizzled ----
    for (int e = tid * 4; e < 16 * NNEUR; e += 256 * 4) {
        int row = e >> 10;
        int k   = e & 1023;
        float4 wv = *(const float4*)(Wr + (size_t)(i0 + row) * NNEUR + k);
        int ksw = k ^ ((row & 7) << 3);   // bank-spread swizzle (bits 3..5)
        float wa[4] = {wv.x, wv.y, wv.z, wv.w};
        #pragma unroll
        for (int j = 0; j < 4; ++j) {
            float fw = wa[j];
            unsigned short hb = f2bf_rn(fw);
            float hf = __uint_as_float((unsigned)hb << 16);
            float rm = fw - hf;                       // exact (Sterbenz)
            unsigned short mb = f2bf_rn(rm);
            float mf = __uint_as_float((unsigned)mb << 16);
            float rl = rm - mf;                       // exact; fits bf16 exactly
            unsigned short lb = f2bf_rn(rl);
            wlds[0 * 16384 + row * 1024 + ksw + j] = hb;
            wlds[1 * 16384 + row * 1024 + ksw + j] = mb;
            wlds[2 * 16384 + row * 1024 + ksw + j] = lb;
        }
    }
    __syncthreads();

    const float brv = br[i0 + c];
    float vreg[4] = {0.f, 0.f, 0.f, 0.f};
    const size_t BN = (size_t)BATCH * NNEUR;

    for (int t = 0; t < T_STEPS; ++t) {
        // prefetch tx for epilogue lanes (waves 0,1 own the outputs)
        float txv[4];
        if (w < 2) {
            #pragma unroll
            for (int j = 0; j < 4; ++j)
                txv[j] = tx[(size_t)t * BN + (size_t)(b0 + w * 16 + kg * 4 + j) * NNEUR + i0 + c];
        }

        f32x4 acc = {0.f, 0.f, 0.f, 0.f};
        if (t > 0) {
            // A-frags: y[t-1] rows (this wg's batches), f32 0/1 -> bf16 by >>16 (exact)
            const unsigned* yprev = (const unsigned*)(out + (size_t)(t - 1) * BN
                                    + (size_t)(b0 + r * 16 + c) * NNEUR + h * 512 + kg * 8);
            short8 afr[16];
            #pragma unroll
            for (int ks = 0; ks < 16; ++ks) {
                uint4 ua = *(const uint4*)(yprev + ks * 32);
                uint4 ub = *(const uint4*)(yprev + ks * 32 + 4);
                U8 f;
                f.u[0] = (ua.x >> 16) | (ua.y & 0xFFFF0000u);
                f.u[1] = (ua.z >> 16) | (ua.w & 0xFFFF0000u);
                f.u[2] = (ub.x >> 16) | (ub.y & 0xFFFF0000u);
                f.u[3] = (ub.z >> 16) | (ub.w & 0xFFFF0000u);
                afr[ks] = f.s;
            }
            #pragma unroll
            for (int mat = 0; mat < 3; ++mat) {
                #pragma unroll
                for (int ks = 0; ks < 16; ++ks) {
                    int kel = h * 512 + ks * 32 + kg * 8;
                    int sw  = kel ^ ((c & 7) << 3);
                    short8 bfr = *(const short8*)(wlds + mat * 16384 + c * 1024 + sw);
                    acc = __builtin_amdgcn_mfma_f32_16x16x32_bf16(afr[ks], bfr, acc, 0, 0, 0);
                }
            }
        }

        // cross-wave K-reduce: waves 2,3 (k-half 1) publish partials
        if (w >= 2) {
            #pragma unroll
            for (int j = 0; j < 4; ++j)
                red[r * 256 + (kg * 4 + j) * 16 + c] = acc[j];
        }
        __syncthreads();

        if (w < 2) {
            float* op = out + (size_t)t * BN;
            #pragma unroll
            for (int j = 0; j < 4; ++j) {
                float z  = acc[j] + red[w * 256 + (kg * 4 + j) * 16 + c];
                float x  = (txv[j] + z) + brv;          // reference op order
                float vv = DECAY_F * vreg[j] + x;
                float s  = (vv > THRESH) ? 1.0f : 0.0f;
                vreg[j]  = (vv > THRESH) ? 0.0f : vv;   // hard reset to rest=0
                op[(size_t)(b0 + w * 16 + kg * 4 + j) * NNEUR + i0 + c] = s;
            }
        }

        // ---- group barrier (64 wgs sharing bb), skipped after last step ----
        __threadfence();        // release this wg's out-writes agent-wide
        __syncthreads();
        if (t < T_STEPS - 1) {
            if (tid == 0) {
                atomicAdd(&cnt[bb * T_STEPS + t], 1);
                while (__hip_atomic_load(&cnt[bb * T_STEPS + t],
                                         __ATOMIC_RELAXED, __HIP_MEMORY_SCOPE_AGENT) != WPG) {}
            }
            __syncthreads();
            __threadfence();    // acquire: invalidate caches before reading peers' spikes
        }
    }
}

extern "C" void kernel_launch(void* const* d_in, const int* in_sizes, int n_in,
                              void* d_out, int out_size, void* d_ws, size_t ws_size,
                              hipStream_t stream)
{
    const float* tx = (const float*)d_in[0];
    const float* Wr = (const float*)d_in[1];
    const float* br = (const float*)d_in[2];
    float* out = (float*)d_out;
    int* cnt   = (int*)d_ws;   // 4KB barrier counters

    const int lds_bytes = 3 * 16 * 1024 * 2 + 2 * 16 * 16 * 4;  // 100352
    hipFuncSetAttribute(reinterpret_cast<const void*>(rlif_persist),
                        hipFuncAttributeMaxDynamicSharedMemorySize, lds_bytes);

    rlif_init<<<dim3(4), dim3(256), 0, stream>>>(cnt);
    rlif_persist<<<dim3(256), dim3(256), lds_bytes, stream>>>(tx, Wr, br, out, cnt);
}

// Round 5
// 1350.791 us; speedup vs baseline: 7.4930x; 7.4930x over previous
//
#include <hip/hip_runtime.h>

// RLIF forward, persistent kernel, stamp-in-word sync + round-2-bitwise datapath.
// Differential vs round 4: the ONLY change is reverting the MFMA accumulation to
// round 2's proven single-chain order (for mat: for ks: acc=mfma), so given
// correct spike bits the fp32 arithmetic is bit-identical to the round-2 PASS.
// Theory: rounds 3/4 failed on a ~1e-7 reassociation flip of a marginal spike
// (3 separate acc chains), not on sync.

#define T_STEPS 256
#define BATCH   128
#define NNEUR   1024
#define DECAY_F 0.2f
#define THRESH  0.3f

typedef __attribute__((ext_vector_type(8))) short short8;
typedef __attribute__((ext_vector_type(4))) float f32x4;

union FU { short8 s; unsigned u[4]; };

__device__ __forceinline__ unsigned short f2bf_rn(float x) {
    unsigned u = __float_as_uint(x);
    return (unsigned short)((u + 0x7FFFu + ((u >> 16) & 1u)) >> 16);
}

__global__ void rlif_init(unsigned* __restrict__ ybits) {
    int i = blockIdx.x * 256 + threadIdx.x;
    if (i < 3 * BATCH * 64) ybits[i] = 0xFFFF0000u;   // stamp 0xFFFF: never matches t
}

__global__ __launch_bounds__(256, 1)
void rlif_persist(const float* __restrict__ tx,   // [T][B][N]
                  const float* __restrict__ Wr,   // [N][N]
                  const float* __restrict__ br,   // [N]
                  float* __restrict__ out,        // [T][B][N]
                  unsigned* __restrict__ ybits)   // [3][128][64] stamped words
{
    extern __shared__ char smem[];
    unsigned short* wlds = (unsigned short*)smem;        // 3 * [16][1024] bf16, swizzled
    float* red = (float*)(smem + 3 * 16 * 1024 * 2);     // [2][16][16] f32 k-reduce
    unsigned short* ys = (unsigned short*)(smem + 3 * 16 * 1024 * 2 + 2 * 16 * 16 * 4); // [32][66]

    const int tid = threadIdx.x;
    const int bb  = blockIdx.x >> 6;   // 0..3  batch-block (32 batches)
    const int ib  = blockIdx.x & 63;   // 0..63 neuron-block (16 neurons)
    const int i0  = ib * 16;
    const int b0  = bb * 32;
    const int w   = tid >> 6;          // wave 0..3
    const int l   = tid & 63;
    const int c   = l & 15;
    const int kg  = l >> 4;
    const int r   = w & 1;             // row-tile
    const int h   = w >> 1;            // k-half

    // ---- one-time: stage Wr rows [i0, i0+16) as exact 3-way bf16 split, swizzled ----
    for (int e = tid * 4; e < 16 * NNEUR; e += 256 * 4) {
        int row = e >> 10;
        int k   = e & 1023;
        float4 wv = *(const float4*)(Wr + (size_t)(i0 + row) * NNEUR + k);
        int ksw = k ^ ((row & 7) << 3);
        float wa[4] = {wv.x, wv.y, wv.z, wv.w};
        #pragma unroll
        for (int j = 0; j < 4; ++j) {
            float fw = wa[j];
            unsigned short hb = f2bf_rn(fw);
            float hf = __uint_as_float((unsigned)hb << 16);
            float rm = fw - hf;
            unsigned short mb = f2bf_rn(rm);
            float mf = __uint_as_float((unsigned)mb << 16);
            float rl = rm - mf;
            unsigned short lb = f2bf_rn(rl);
            wlds[0 * 16384 + row * 1024 + ksw + j] = hb;
            wlds[1 * 16384 + row * 1024 + ksw + j] = mb;
            wlds[2 * 16384 + row * 1024 + ksw + j] = lb;
        }
    }
    __syncthreads();

    const float brv = br[i0 + c];
    float vreg[4] = {0.f, 0.f, 0.f, 0.f};
    const size_t BN = (size_t)BATCH * NNEUR;

    for (int t = 0; t < T_STEPS; ++t) {
        float txv[4];
        if (w < 2) {
            #pragma unroll
            for (int j = 0; j < 4; ++j)
                txv[j] = tx[(size_t)t * BN + (size_t)(b0 + w * 16 + kg * 4 + j) * NNEUR + i0 + c];
        }

        // ---- stage spikes of step t-1 into LDS (poll stamped words, RMW reads) ----
        if (t > 0) {
            unsigned* buf = ybits + (size_t)((t - 1) % 3) * (BATCH * 64);
            const unsigned want = (unsigned)(t - 1);
            unsigned pend = 0xFFu;    // 8 words per thread: wi = k*256 + tid
            for (;;) {
                #pragma unroll
                for (int k = 0; k < 8; ++k) {
                    if (pend & (1u << k)) {
                        int wi  = (k << 8) | tid;       // 0..2047
                        int row = wi >> 6;              // 0..31 (batch within block)
                        int col = wi & 63;              // writer wg column
                        unsigned v = atomicOr(&buf[(b0 + row) * 64 + col], 0u);
                        if ((v >> 16) == want) {
                            ys[row * 66 + col] = (unsigned short)(v & 0xFFFFu);
                            pend &= ~(1u << k);
                        }
                    }
                }
                if (!pend) break;
                __builtin_amdgcn_s_sleep(1);
            }
        }
        __syncthreads();

        f32x4 acc = {0.f, 0.f, 0.f, 0.f};
        if (t > 0) {
            // A-frags: identical bit patterns to round 2 (bf16 1.0 / 0.0)
            short8 afr[16];
            #pragma unroll
            for (int ks = 0; ks < 16; ++ks) {
                unsigned wv = *(const unsigned*)(ys + (r * 16 + c) * 66 + 2 * (h * 16 + ks));
                unsigned byt = (wv >> (kg * 8)) & 0xFFu;
                FU f;
                #pragma unroll
                for (int q = 0; q < 4; ++q) {
                    f.u[q] = (((byt >> (2 * q)) & 1u) ? 0x00003F80u : 0u)
                           | (((byt >> (2 * q + 1)) & 1u) ? 0x3F800000u : 0u);
                }
                afr[ks] = f.s;
            }
            // single accumulator chain, mat-outer / ks-inner — round 2's exact order
            #pragma unroll
            for (int mat = 0; mat < 3; ++mat) {
                #pragma unroll
                for (int ks = 0; ks < 16; ++ks) {
                    int kel = h * 512 + ks * 32 + kg * 8;
                    int sw  = kel ^ ((c & 7) << 3);
                    short8 bfr = *(const short8*)(wlds + mat * 16384 + c * 1024 + sw);
                    acc = __builtin_amdgcn_mfma_f32_16x16x32_bf16(afr[ks], bfr, acc, 0, 0, 0);
                }
            }
        }

        if (w >= 2) {
            #pragma unroll
            for (int j = 0; j < 4; ++j)
                red[r * 256 + (kg * 4 + j) * 16 + c] = acc[j];
        }
        __syncthreads();

        if (w < 2) {
            float* op = out + (size_t)t * BN;
            unsigned* pbuf = ybits + (size_t)(t % 3) * (BATCH * 64);
            #pragma unroll
            for (int j = 0; j < 4; ++j) {
                float z  = acc[j] + red[w * 256 + (kg * 4 + j) * 16 + c];
                float x  = (txv[j] + z) + brv;
                float vv = DECAY_F * vreg[j] + x;
                int   sp = vv > THRESH;
                vreg[j]  = sp ? 0.f : vv;
                op[(size_t)(b0 + w * 16 + kg * 4 + j) * NNEUR + i0 + c] = sp ? 1.f : 0.f;
                unsigned long long m = __ballot(sp != 0);
                if (c == j) {
                    unsigned u16v = (unsigned)((m >> (kg * 16)) & 0xFFFFu);
                    atomicExch(&pbuf[(b0 + w * 16 + kg * 4 + j) * 64 + ib],
                               ((unsigned)t << 16) | u16v);
                }
            }
        }
        // no end-of-step barrier: stamp polling is the synchronization
    }
}

extern "C" void kernel_launch(void* const* d_in, const int* in_sizes, int n_in,
                              void* d_out, int out_size, void* d_ws, size_t ws_size,
                              hipStream_t stream)
{
    const float* tx = (const float*)d_in[0];
    const float* Wr = (const float*)d_in[1];
    const float* br = (const float*)d_in[2];
    float* out = (float*)d_out;
    unsigned* ybits = (unsigned*)d_ws;   // [3][128][64] u32 = 96 KB

    const int lds_bytes = 3 * 16 * 1024 * 2 + 2 * 16 * 16 * 4 + 32 * 66 * 2;  // 103552
    hipFuncSetAttribute(reinterpret_cast<const void*>(rlif_persist),
                        hipFuncAttributeMaxDynamicSharedMemorySize, lds_bytes);

    rlif_init<<<dim3(96), dim3(256), 0, stream>>>(ybits);
    rlif_persist<<<dim3(256), dim3(256), lds_bytes, stream>>>(tx, Wr, br, out, ybits);
}